// Round 1
// baseline (361.313 us; speedup 1.0000x reference)
//
#include <hip/hip_runtime.h>

// N=4194304 rows, C=8. Output: scalar mean(ce_loss * value).
// Memory-bound: 128MB inputs + 16MB targets -> ~23us floor at 6.3 TB/s.

#define N_ROWS 4194304
#define TPB 256

__global__ __launch_bounds__(TPB) void coga_kernel(
    const float* __restrict__ x,
    const int* __restrict__ tgt,
    float* __restrict__ out)
{
    // inv(T_COV) = [[2.4, 1.6],[1.6, 2.4]]        (T_COV=[[.75,-.5],[-.5,.75]])
    // inv(F_COV) = [[10.3030..,-9.6969..],[...]]  (F_COV=[[.85,.8],[.8,.85]])
    const float aT = 2.4f,                bT = 1.6f;
    const float aF = 10.30303030303030f,  bF = -9.69696969696970f;
    const float muT0 = 0.5f, muT1 = 0.5f;
    const float muF0 = 0.3f, muF1 = 0.15f;

    int row = blockIdx.x * TPB + threadIdx.x;
    float contrib = 0.0f;
    if (row < N_ROWS) {
        const float4* p = (const float4*)(x + (size_t)row * 8);
        float4 v0 = p[0];
        float4 v1 = p[1];
        int t = tgt[row];

        // top-2 of logits (exp is monotone, so this gives top-2 of probs)
        float m1 = v0.x, m2 = -INFINITY;
        {
            float xs[7] = {v0.y, v0.z, v0.w, v1.x, v1.y, v1.z, v1.w};
            #pragma unroll
            for (int i = 0; i < 7; ++i) {
                float xi = xs[i];
                float hi = fmaxf(xi, m1);
                float lo = fminf(xi, m1);
                m2 = fmaxf(m2, lo);
                m1 = hi;
            }
        }

        // sum of exp(x - m1)
        float s = __expf(v0.x - m1) + __expf(v0.y - m1) +
                  __expf(v0.z - m1) + __expf(v0.w - m1) +
                  __expf(v1.x - m1) + __expf(v1.y - m1) +
                  __expf(v1.z - m1) + __expf(v1.w - m1);

        // x[t] via cndmask chain (no scratch array)
        float xt = v0.x;
        xt = (t == 1) ? v0.y : xt;
        xt = (t == 2) ? v0.z : xt;
        xt = (t == 3) ? v0.w : xt;
        xt = (t == 4) ? v1.x : xt;
        xt = (t == 5) ? v1.y : xt;
        xt = (t == 6) ? v1.z : xt;
        xt = (t == 7) ? v1.w : xt;

        float inv_s = 1.0f / s;
        float logs  = __logf(s);
        float p_t   = __expf(xt - m1) * inv_s;
        float ce    = (m1 - xt) + logs;          // -logp[target]

        bool  is_t  = (xt == m1);                // p_t is the max prob
        float p2    = __expf(m2 - m1) * inv_s;   // second-max prob
        float pmax  = inv_s;                     // max prob = exp(0)/s
        float p_neg = is_t ? p2 : pmax;

        float a  = is_t ? aT   : aF;
        float b  = is_t ? bT   : bF;
        float dx = p_t   - (is_t ? muT0 : muF0);
        float dy = p_neg - (is_t ? muT1 : muF1);

        float q     = a * (dx * dx + dy * dy) + 2.0f * b * dx * dy;
        float value = __expf(-0.5f * q);

        contrib = ce * value;
    }

    // wave-64 reduction
    #pragma unroll
    for (int off = 32; off > 0; off >>= 1)
        contrib += __shfl_down(contrib, off, 64);

    __shared__ float wsum[TPB / 64];
    int lane = threadIdx.x & 63;
    int wid  = threadIdx.x >> 6;
    if (lane == 0) wsum[wid] = contrib;
    __syncthreads();

    if (threadIdx.x == 0) {
        float bs = 0.0f;
        #pragma unroll
        for (int w = 0; w < TPB / 64; ++w) bs += wsum[w];
        atomicAdd(out, bs * (1.0f / (float)N_ROWS));
    }
}

extern "C" void kernel_launch(void* const* d_in, const int* in_sizes, int n_in,
                              void* d_out, int out_size, void* d_ws, size_t ws_size,
                              hipStream_t stream) {
    const float* x   = (const float*)d_in[0];
    const int*   tgt = (const int*)d_in[1];
    float*       out = (float*)d_out;

    hipMemsetAsync(out, 0, sizeof(float), stream);

    int grid = (N_ROWS + TPB - 1) / TPB;  // 16384 blocks
    coga_kernel<<<grid, TPB, 0, stream>>>(x, tgt, out);
}

// Round 2
// 200.075 us; speedup vs baseline: 1.8059x; 1.8059x over previous
//
#include <hip/hip_runtime.h>

// N=4194304 rows, C=8. Output: scalar mean(ce_loss * value).
// Memory-bound: ~150MB read-once -> ~24us floor at 6.3 TB/s.
// R1 lesson: 16384 same-address atomicAdds serialized (~200us). Use
// two-stage reduction through d_ws instead.

#define N_ROWS 4194304
#define TPB 256
#define NBLOCKS (N_ROWS / TPB)   // 16384

__device__ __forceinline__ float row_contrib(float4 v0, float4 v1, int t) {
    // inv(T_COV) = [[2.4, 1.6],[1.6, 2.4]]        (T_COV=[[.75,-.5],[-.5,.75]])
    // inv(F_COV) = [[10.3030..,-9.6969..],[...]]  (F_COV=[[.85,.8],[.8,.85]])
    const float aT = 2.4f,                bT = 1.6f;
    const float aF = 10.30303030303030f,  bF = -9.69696969696970f;

    // top-2 of logits (exp is monotone -> top-2 of probs)
    float m1 = v0.x, m2 = -INFINITY;
    float xs[7] = {v0.y, v0.z, v0.w, v1.x, v1.y, v1.z, v1.w};
    #pragma unroll
    for (int i = 0; i < 7; ++i) {
        float xi = xs[i];
        float hi = fmaxf(xi, m1);
        float lo = fminf(xi, m1);
        m2 = fmaxf(m2, lo);
        m1 = hi;
    }

    float s = __expf(v0.x - m1) + __expf(v0.y - m1) +
              __expf(v0.z - m1) + __expf(v0.w - m1) +
              __expf(v1.x - m1) + __expf(v1.y - m1) +
              __expf(v1.z - m1) + __expf(v1.w - m1);

    float xt = v0.x;
    xt = (t == 1) ? v0.y : xt;
    xt = (t == 2) ? v0.z : xt;
    xt = (t == 3) ? v0.w : xt;
    xt = (t == 4) ? v1.x : xt;
    xt = (t == 5) ? v1.y : xt;
    xt = (t == 6) ? v1.z : xt;
    xt = (t == 7) ? v1.w : xt;

    float inv_s = 1.0f / s;
    float logs  = __logf(s);
    float p_t   = __expf(xt - m1) * inv_s;
    float ce    = (m1 - xt) + logs;          // -logp[target]

    bool  is_t  = (xt == m1);
    float p2    = __expf(m2 - m1) * inv_s;   // second-max prob
    float pmax  = inv_s;                     // max prob = exp(0)/s
    float p_neg = is_t ? p2 : pmax;

    float a  = is_t ? aT : aF;
    float b  = is_t ? bT : bF;
    float dx = p_t   - (is_t ? 0.5f : 0.3f);
    float dy = p_neg - (is_t ? 0.5f : 0.15f);

    float q = a * (dx * dx + dy * dy) + 2.0f * b * dx * dy;
    return ce * __expf(-0.5f * q);
}

__device__ __forceinline__ float block_reduce(float v, float* wsum) {
    #pragma unroll
    for (int off = 32; off > 0; off >>= 1)
        v += __shfl_down(v, off, 64);
    int lane = threadIdx.x & 63;
    int wid  = threadIdx.x >> 6;
    if (lane == 0) wsum[wid] = v;
    __syncthreads();
    float bs = 0.0f;
    if (threadIdx.x == 0) {
        #pragma unroll
        for (int w = 0; w < TPB / 64; ++w) bs += wsum[w];
    }
    return bs;
}

// Stage 1: one row per thread, per-block partial -> d_ws[blockIdx]. No atomics.
__global__ __launch_bounds__(TPB) void coga_stage1(
    const float* __restrict__ x,
    const int* __restrict__ tgt,
    float* __restrict__ partials)
{
    int row = blockIdx.x * TPB + threadIdx.x;
    const float4* p = (const float4*)(x + (size_t)row * 8);
    float4 v0 = p[0];
    float4 v1 = p[1];
    int t = tgt[row];
    float contrib = row_contrib(v0, v1, t);

    __shared__ float wsum[TPB / 64];
    float bs = block_reduce(contrib, wsum);
    if (threadIdx.x == 0) partials[blockIdx.x] = bs;
}

// Stage 2: single block reduces NBLOCKS partials, writes the mean.
__global__ __launch_bounds__(1024) void coga_stage2(
    const float* __restrict__ partials,
    float* __restrict__ out)
{
    float s = 0.0f;
    for (int i = threadIdx.x; i < NBLOCKS; i += 1024)
        s += partials[i];

    #pragma unroll
    for (int off = 32; off > 0; off >>= 1)
        s += __shfl_down(s, off, 64);

    __shared__ float wsum[1024 / 64];
    int lane = threadIdx.x & 63;
    int wid  = threadIdx.x >> 6;
    if (lane == 0) wsum[wid] = s;
    __syncthreads();

    if (threadIdx.x == 0) {
        float bs = 0.0f;
        #pragma unroll
        for (int w = 0; w < 1024 / 64; ++w) bs += wsum[w];
        out[0] = bs * (1.0f / (float)N_ROWS);
    }
}

// Fallback (ws too small): grid-stride + few atomics.
__global__ __launch_bounds__(TPB) void coga_fallback(
    const float* __restrict__ x,
    const int* __restrict__ tgt,
    float* __restrict__ out)
{
    float acc = 0.0f;
    int stride = gridDim.x * TPB;
    for (int row = blockIdx.x * TPB + threadIdx.x; row < N_ROWS; row += stride) {
        const float4* p = (const float4*)(x + (size_t)row * 8);
        acc += row_contrib(p[0], p[1], tgt[row]);
    }
    __shared__ float wsum[TPB / 64];
    float bs = block_reduce(acc, wsum);
    if (threadIdx.x == 0) atomicAdd(out, bs * (1.0f / (float)N_ROWS));
}

extern "C" void kernel_launch(void* const* d_in, const int* in_sizes, int n_in,
                              void* d_out, int out_size, void* d_ws, size_t ws_size,
                              hipStream_t stream) {
    const float* x   = (const float*)d_in[0];
    const int*   tgt = (const int*)d_in[1];
    float*       out = (float*)d_out;

    if (ws_size >= NBLOCKS * sizeof(float)) {
        float* partials = (float*)d_ws;
        coga_stage1<<<NBLOCKS, TPB, 0, stream>>>(x, tgt, partials);
        coga_stage2<<<1, 1024, 0, stream>>>(partials, out);
    } else {
        hipMemsetAsync(out, 0, sizeof(float), stream);
        coga_fallback<<<512, TPB, 0, stream>>>(x, tgt, out);
    }
}

// Round 3
// 199.888 us; speedup vs baseline: 1.8076x; 1.0009x over previous
//
#include <hip/hip_runtime.h>

// N=4194304 rows, C=8. Output: scalar mean(ce_loss * value).
// Memory-bound: ~150MB read-once -> ~24us floor at 6.3 TB/s.
// R1 lesson: 16384 same-address atomics serialized (~200us) -> two-stage.
// R2 lesson: 16384 tiny blocks (1 row/thread) are latency-bound; harness
//   d_ws poison fill (77us) + d_in restore dominate the profile. Grid-stride
//   with 8 rows/thread + batched loads for MLP.

#define N_ROWS 4194304
#define TPB 256
#define GRID 2048
#define RPT (N_ROWS / (GRID * TPB))   // 8 rows per thread

__device__ __forceinline__ float row_contrib(float4 v0, float4 v1, int t) {
    // inv(T_COV) = [[2.4, 1.6],[1.6, 2.4]]        (T_COV=[[.75,-.5],[-.5,.75]])
    // inv(F_COV) = [[10.3030..,-9.6969..],[...]]  (F_COV=[[.85,.8],[.8,.85]])
    const float aT = 2.4f,                bT = 1.6f;
    const float aF = 10.30303030303030f,  bF = -9.69696969696970f;

    // top-2 of logits (exp is monotone -> top-2 of probs)
    float m1 = v0.x, m2 = -INFINITY;
    float xs[7] = {v0.y, v0.z, v0.w, v1.x, v1.y, v1.z, v1.w};
    #pragma unroll
    for (int i = 0; i < 7; ++i) {
        float xi = xs[i];
        float hi = fmaxf(xi, m1);
        float lo = fminf(xi, m1);
        m2 = fmaxf(m2, lo);
        m1 = hi;
    }

    float s = __expf(v0.x - m1) + __expf(v0.y - m1) +
              __expf(v0.z - m1) + __expf(v0.w - m1) +
              __expf(v1.x - m1) + __expf(v1.y - m1) +
              __expf(v1.z - m1) + __expf(v1.w - m1);

    float xt = v0.x;
    xt = (t == 1) ? v0.y : xt;
    xt = (t == 2) ? v0.z : xt;
    xt = (t == 3) ? v0.w : xt;
    xt = (t == 4) ? v1.x : xt;
    xt = (t == 5) ? v1.y : xt;
    xt = (t == 6) ? v1.z : xt;
    xt = (t == 7) ? v1.w : xt;

    float inv_s = 1.0f / s;
    float logs  = __logf(s);
    float p_t   = __expf(xt - m1) * inv_s;
    float ce    = (m1 - xt) + logs;          // -logp[target]

    bool  is_t  = (xt == m1);
    float p2    = __expf(m2 - m1) * inv_s;   // second-max prob
    float pmax  = inv_s;                     // max prob = exp(0)/s
    float p_neg = is_t ? p2 : pmax;

    float a  = is_t ? aT : aF;
    float b  = is_t ? bT : bF;
    float dx = p_t   - (is_t ? 0.5f : 0.3f);
    float dy = p_neg - (is_t ? 0.5f : 0.15f);

    float q = a * (dx * dx + dy * dy) + 2.0f * b * dx * dy;
    return ce * __expf(-0.5f * q);
}

// Stage 1: grid-stride, 8 rows/thread, loads batched 4-wide for MLP.
__global__ __launch_bounds__(TPB) void coga_stage1(
    const float4* __restrict__ x4,
    const int* __restrict__ tgt,
    float* __restrict__ partials)
{
    const int tid    = blockIdx.x * TPB + threadIdx.x;
    const int stride = GRID * TPB;

    float acc = 0.0f;
    #pragma unroll
    for (int k = 0; k < RPT; k += 4) {
        float4 a0[4], a1[4];
        int    t[4];
        #pragma unroll
        for (int j = 0; j < 4; ++j) {
            size_t row = (size_t)tid + (size_t)(k + j) * stride;
            a0[j] = x4[2 * row];
            a1[j] = x4[2 * row + 1];
            t[j]  = tgt[row];
        }
        #pragma unroll
        for (int j = 0; j < 4; ++j)
            acc += row_contrib(a0[j], a1[j], t[j]);
    }

    // wave-64 + LDS block reduction
    #pragma unroll
    for (int off = 32; off > 0; off >>= 1)
        acc += __shfl_down(acc, off, 64);

    __shared__ float wsum[TPB / 64];
    int lane = threadIdx.x & 63;
    int wid  = threadIdx.x >> 6;
    if (lane == 0) wsum[wid] = acc;
    __syncthreads();

    if (threadIdx.x == 0) {
        float bs = 0.0f;
        #pragma unroll
        for (int w = 0; w < TPB / 64; ++w) bs += wsum[w];
        partials[blockIdx.x] = bs;
    }
}

// Stage 2: single block reduces GRID partials, writes the mean.
__global__ __launch_bounds__(1024) void coga_stage2(
    const float* __restrict__ partials,
    float* __restrict__ out)
{
    float s = 0.0f;
    for (int i = threadIdx.x; i < GRID; i += 1024)
        s += partials[i];

    #pragma unroll
    for (int off = 32; off > 0; off >>= 1)
        s += __shfl_down(s, off, 64);

    __shared__ float wsum[1024 / 64];
    int lane = threadIdx.x & 63;
    int wid  = threadIdx.x >> 6;
    if (lane == 0) wsum[wid] = s;
    __syncthreads();

    if (threadIdx.x == 0) {
        float bs = 0.0f;
        #pragma unroll
        for (int w = 0; w < 1024 / 64; ++w) bs += wsum[w];
        out[0] = bs * (1.0f / (float)N_ROWS);
    }
}

// Fallback (ws too small): grid-stride + few atomics.
__global__ __launch_bounds__(TPB) void coga_fallback(
    const float* __restrict__ x,
    const int* __restrict__ tgt,
    float* __restrict__ out)
{
    float acc = 0.0f;
    int stride = gridDim.x * TPB;
    for (int row = blockIdx.x * TPB + threadIdx.x; row < N_ROWS; row += stride) {
        const float4* p = (const float4*)(x + (size_t)row * 8);
        acc += row_contrib(p[0], p[1], tgt[row]);
    }
    #pragma unroll
    for (int off = 32; off > 0; off >>= 1)
        acc += __shfl_down(acc, off, 64);
    __shared__ float wsum[TPB / 64];
    int lane = threadIdx.x & 63;
    int wid  = threadIdx.x >> 6;
    if (lane == 0) wsum[wid] = acc;
    __syncthreads();
    if (threadIdx.x == 0) {
        float bs = 0.0f;
        #pragma unroll
        for (int w = 0; w < TPB / 64; ++w) bs += wsum[w];
        atomicAdd(out, bs * (1.0f / (float)N_ROWS));
    }
}

extern "C" void kernel_launch(void* const* d_in, const int* in_sizes, int n_in,
                              void* d_out, int out_size, void* d_ws, size_t ws_size,
                              hipStream_t stream) {
    const float* x   = (const float*)d_in[0];
    const int*   tgt = (const int*)d_in[1];
    float*       out = (float*)d_out;

    if (ws_size >= GRID * sizeof(float)) {
        float* partials = (float*)d_ws;
        coga_stage1<<<GRID, TPB, 0, stream>>>((const float4*)x, tgt, partials);
        coga_stage2<<<1, 1024, 0, stream>>>(partials, out);
    } else {
        hipMemsetAsync(out, 0, sizeof(float), stream);
        coga_fallback<<<512, TPB, 0, stream>>>(x, tgt, out);
    }
}